// Round 1
// baseline (564.042 us; speedup 1.0000x reference)
//
#include <hip/hip_runtime.h>
#include <hip/hip_bf16.h>
#include <stdint.h>

#define NTOK 8192   // B*S
#define MDIM 1024
#define HDIM 4096
#define NEXP 8
#define CAP  2048   // int(1.0 * 2 * 8192 // 8)

typedef __attribute__((ext_vector_type(8))) short bf16x8;
typedef __attribute__((ext_vector_type(4))) float f32x4;

__device__ __forceinline__ ushort f2bf(float f) {
  uint32_t u = __builtin_bit_cast(uint32_t, f);
  u += 0x7FFFu + ((u >> 16) & 1u);          // round-to-nearest-even
  return (ushort)(u >> 16);
}
__device__ __forceinline__ float bf2f(ushort h) {
  uint32_t u = ((uint32_t)h) << 16;
  return __builtin_bit_cast(float, u);
}

// ---------------- gate: logits = x@wg (f64 accum), softmax-top2, normalize ----
__global__ __launch_bounds__(256) void gate_kernel(const float* __restrict__ x,
                                                   const float* __restrict__ wg,
                                                   int* __restrict__ topi,
                                                   float* __restrict__ gatev) {
  const int lane = threadIdx.x & 63;
  const int n = blockIdx.x * 4 + (threadIdx.x >> 6);   // one wave per token
  const float* xr = x + (size_t)n * MDIM;
  double acc[NEXP];
#pragma unroll
  for (int e = 0; e < NEXP; ++e) acc[e] = 0.0;
#pragma unroll
  for (int c = 0; c < 4; ++c) {
    float4 xv = *(const float4*)(xr + c * 256 + lane * 4);
    float xs[4] = {xv.x, xv.y, xv.z, xv.w};
#pragma unroll
    for (int j = 0; j < 4; ++j) {
      int m = c * 256 + lane * 4 + j;
      float4 w0 = *(const float4*)(wg + m * 8);
      float4 w1 = *(const float4*)(wg + m * 8 + 4);
      double xd = (double)xs[j];
      acc[0] += xd * (double)w0.x; acc[1] += xd * (double)w0.y;
      acc[2] += xd * (double)w0.z; acc[3] += xd * (double)w0.w;
      acc[4] += xd * (double)w1.x; acc[5] += xd * (double)w1.y;
      acc[6] += xd * (double)w1.z; acc[7] += xd * (double)w1.w;
    }
  }
#pragma unroll
  for (int off = 32; off >= 1; off >>= 1) {
#pragma unroll
    for (int e = 0; e < NEXP; ++e) acc[e] += __shfl_xor(acc[e], off, 64);
  }
  if (lane == 0) {
    int i0 = 0;
#pragma unroll
    for (int e = 1; e < NEXP; ++e) if (acc[e] > acc[i0]) i0 = e;
    int i1 = (i0 == 0) ? 1 : 0;
#pragma unroll
    for (int e = 0; e < NEXP; ++e) if (e != i0 && acc[e] > acc[i1]) i1 = e;
    // normalized top-2 of softmax == softmax over the two logits
    double e1 = exp(acc[i1] - acc[i0]);
    double s = 1.0 + e1;
    topi[n * 2 + 0] = i0; topi[n * 2 + 1] = i1;
    gatev[n * 2 + 0] = (float)(1.0 / s);
    gatev[n * 2 + 1] = (float)(e1 / s);
  }
}

// ---------------- slot-major cumulative positions (order: j = k*NTOK + n) ----
__global__ __launch_bounds__(256) void scan_kernel(const int* __restrict__ topi,
                                                   int* __restrict__ pos) {
  __shared__ int cnt[256][NEXP];
  const int t = threadIdx.x;
#pragma unroll
  for (int e = 0; e < NEXP; ++e) cnt[t][e] = 0;
  for (int i = 0; i < 64; ++i) {
    int j = t * 64 + i;
    int e = topi[(j & (NTOK - 1)) * 2 + (j >> 13)];
    cnt[t][e]++;
  }
  __syncthreads();
  if (t < NEXP) {          // exclusive scan over the 256 thread-chunks
    int run = 0;
    for (int i = 0; i < 256; ++i) { int v = cnt[i][t]; cnt[i][t] = run; run += v; }
  }
  __syncthreads();
  for (int i = 0; i < 64; ++i) {
    int j = t * 64 + i;
    int idx = (j & (NTOK - 1)) * 2 + (j >> 13);
    int e = topi[idx];
    pos[idx] = cnt[t][e]++;
  }
}

// ---------------- zero the dispatch buffer -----------------------------------
__global__ __launch_bounds__(256) void zero_kernel(uint4* __restrict__ p) {
  int t = blockIdx.x * 256 + threadIdx.x;
#pragma unroll
  for (int i = 0; i < 4; ++i) {
    uint4 z; z.x = 0; z.y = 0; z.z = 0; z.w = 0;
    p[t + i * 524288] = z;   // 2048 blocks * 256 thr * 4 * 16B = 32MB
  }
}

// ---------------- scatter x rows (bf16) into [E,CAP,M] -----------------------
__global__ __launch_bounds__(256) void scatter_kernel(const float* __restrict__ x,
                                                      const int* __restrict__ topi,
                                                      const int* __restrict__ pos,
                                                      ushort* __restrict__ disp) {
  const int lane = threadIdx.x & 63;
  const int n = blockIdx.x * 4 + (threadIdx.x >> 6);
  const float* src = x + (size_t)n * MDIM;
  ushort b[16];
#pragma unroll
  for (int c = 0; c < 4; ++c) {
    float4 v = *(const float4*)(src + c * 256 + lane * 4);
    b[c * 4 + 0] = f2bf(v.x); b[c * 4 + 1] = f2bf(v.y);
    b[c * 4 + 2] = f2bf(v.z); b[c * 4 + 3] = f2bf(v.w);
  }
#pragma unroll
  for (int k = 0; k < 2; ++k) {
    int p = pos[n * 2 + k];
    if (p < CAP) {
      int e = topi[n * 2 + k];
      ushort* dst = disp + ((size_t)(e * CAP + p)) * MDIM;
#pragma unroll
      for (int c = 0; c < 4; ++c) {
        ushort4 o; o.x = b[c*4+0]; o.y = b[c*4+1]; o.z = b[c*4+2]; o.w = b[c*4+3];
        *(ushort4*)(dst + c * 256 + lane * 4) = o;
      }
    }
  }
}

// ---------------- transpose + f32->bf16: in[R][C] -> out[C][R], per expert ---
__global__ __launch_bounds__(256) void transpose_cvt(const float* __restrict__ in,
                                                     ushort* __restrict__ out,
                                                     int R, int C) {
  __shared__ float tile[64][65];
  const int e = blockIdx.z;
  in  += (size_t)e * R * C;
  out += (size_t)e * R * C;
  const int r0 = blockIdx.y * 64, c0 = blockIdx.x * 64;
  const int t = threadIdx.x;
  const int r = t >> 2, cq = t & 3;
#pragma unroll
  for (int i = 0; i < 4; ++i) {
    float4 v = *(const float4*)(in + (size_t)(r0 + r) * C + c0 + cq * 16 + i * 4);
    tile[r][cq * 16 + i * 4 + 0] = v.x; tile[r][cq * 16 + i * 4 + 1] = v.y;
    tile[r][cq * 16 + i * 4 + 2] = v.z; tile[r][cq * 16 + i * 4 + 3] = v.w;
  }
  __syncthreads();
  const int oc = t >> 2, orr0 = (t & 3) * 16;
  ushort o16[16];
#pragma unroll
  for (int i = 0; i < 16; ++i) o16[i] = f2bf(tile[orr0 + i][oc]);
  ushort* dst = out + (size_t)(c0 + oc) * R + r0 + orr0;
  *(uint4*)dst = *(uint4*)&o16[0];
  *(uint4*)(dst + 8) = *(uint4*)&o16[8];
}

// ---------------- bf16 MFMA GEMM: C = A[M,K] * Bt[N,K]^T (+bias, relu) -------
// 128x128 tile, BK=64, 4 waves (2x2), XOR-swizzled LDS (T2), reg staging.
template <bool RELU, bool OUT_BF16>
__global__ __launch_bounds__(256) void gemm_bt(const ushort* __restrict__ A,
                                               const ushort* __restrict__ Bt,
                                               const float* __restrict__ bias,
                                               void* __restrict__ Cout,
                                               int Mrows, int Ncols, int Kdim) {
  __shared__ ushort As[128 * 64];
  __shared__ ushort Bs[128 * 64];
  const int e = blockIdx.z;
  A    += (size_t)e * Mrows * Kdim;
  Bt   += (size_t)e * Ncols * Kdim;
  bias += (size_t)e * Ncols;
  const size_t cbase = (size_t)e * Mrows * Ncols;
  const int m0 = blockIdx.y * 128, n0 = blockIdx.x * 128;
  const int t = threadIdx.x, lane = t & 63, w = t >> 6;
  const int wm = w >> 1, wn = w & 1;
  const int l15 = lane & 15, l4 = lane >> 4;

  f32x4 acc[4][4];
#pragma unroll
  for (int m = 0; m < 4; ++m)
#pragma unroll
    for (int n = 0; n < 4; ++n) acc[m][n] = (f32x4){0.f, 0.f, 0.f, 0.f};

  for (int k0 = 0; k0 < Kdim; k0 += 64) {
    __syncthreads();
    // stage 128x64 A-tile and B-tile; 8 chunks of 8 bf16 per row, swizzled
#pragma unroll
    for (int p = 0; p < 4; ++p) {
      int idx = p * 256 + t;
      int row = idx >> 3, c = idx & 7;
      bf16x8 va = *(const bf16x8*)(A + (size_t)(m0 + row) * Kdim + k0 + c * 8);
      *(bf16x8*)(As + row * 64 + ((c ^ (row & 7)) * 8)) = va;
      bf16x8 vb = *(const bf16x8*)(Bt + (size_t)(n0 + row) * Kdim + k0 + c * 8);
      *(bf16x8*)(Bs + row * 64 + ((c ^ (row & 7)) * 8)) = vb;
    }
    __syncthreads();
#pragma unroll
    for (int kk = 0; kk < 2; ++kk) {
      bf16x8 af[4], bfr[4];
#pragma unroll
      for (int m = 0; m < 4; ++m) {
        int row = wm * 64 + m * 16 + l15;
        af[m] = *(const bf16x8*)(As + row * 64 + (((kk * 4 + l4) ^ (row & 7)) * 8));
      }
#pragma unroll
      for (int n = 0; n < 4; ++n) {
        int row = wn * 64 + n * 16 + l15;
        bfr[n] = *(const bf16x8*)(Bs + row * 64 + (((kk * 4 + l4) ^ (row & 7)) * 8));
      }
#pragma unroll
      for (int m = 0; m < 4; ++m)
#pragma unroll
        for (int n = 0; n < 4; ++n)
          acc[m][n] = __builtin_amdgcn_mfma_f32_16x16x32_bf16(af[m], bfr[n], acc[m][n], 0, 0, 0);
    }
  }
  // epilogue: D[row=(l>>4)*4+r][col=l&15]
#pragma unroll
  for (int n = 0; n < 4; ++n) {
    int col = n0 + wn * 64 + n * 16 + l15;
    float bv = bias[col];
#pragma unroll
    for (int m = 0; m < 4; ++m) {
      int rowb = m0 + wm * 64 + m * 16 + l4 * 4;
#pragma unroll
      for (int r = 0; r < 4; ++r) {
        float v = acc[m][n][r] + bv;
        if (RELU) v = fmaxf(v, 0.f);
        size_t oidx = cbase + (size_t)(rowb + r) * Ncols + col;
        if (OUT_BF16) ((ushort*)Cout)[oidx] = f2bf(v);
        else          ((float*)Cout)[oidx] = v;
      }
    }
  }
}

// ---------------- combine: out[n] = sum_k gate * y[e_k, p_k] -----------------
__global__ __launch_bounds__(256) void combine_kernel(const ushort* __restrict__ y,
                                                      const int* __restrict__ topi,
                                                      const int* __restrict__ pos,
                                                      const float* __restrict__ gatev,
                                                      float* __restrict__ out) {
  const int lane = threadIdx.x & 63;
  const int n = blockIdx.x * 4 + (threadIdx.x >> 6);
  int i0 = topi[n * 2], i1 = topi[n * 2 + 1];
  int p0 = pos[n * 2], p1 = pos[n * 2 + 1];
  float g0 = (p0 < CAP) ? gatev[n * 2] : 0.f;
  float g1 = (p1 < CAP) ? gatev[n * 2 + 1] : 0.f;
  const ushort* y0 = y + (size_t)(i0 * CAP + (p0 < CAP ? p0 : 0)) * MDIM;
  const ushort* y1 = y + (size_t)(i1 * CAP + (p1 < CAP ? p1 : 0)) * MDIM;
  float* o = out + (size_t)n * MDIM;
#pragma unroll
  for (int c = 0; c < 4; ++c) {
    int idx = c * 256 + lane * 4;
    ushort4 a = *(const ushort4*)(y0 + idx);
    ushort4 b = *(const ushort4*)(y1 + idx);
    float4 ov;
    ov.x = g0 * bf2f(a.x) + g1 * bf2f(b.x);
    ov.y = g0 * bf2f(a.y) + g1 * bf2f(b.y);
    ov.z = g0 * bf2f(a.z) + g1 * bf2f(b.z);
    ov.w = g0 * bf2f(a.w) + g1 * bf2f(b.w);
    *(float4*)(o + idx) = ov;
  }
}

extern "C" void kernel_launch(void* const* d_in, const int* in_sizes, int n_in,
                              void* d_out, int out_size, void* d_ws, size_t ws_size,
                              hipStream_t stream) {
  const float* x  = (const float*)d_in[0];
  const float* wg = (const float*)d_in[1];
  const float* w1 = (const float*)d_in[2];
  const float* b1 = (const float*)d_in[3];
  const float* w2 = (const float*)d_in[4];
  const float* b2 = (const float*)d_in[5];
  float* out = (float*)d_out;
  char* ws = (char*)d_ws;

  // workspace layout (224.3 MB total)
  int*    topi  = (int*)(ws);
  int*    pos   = (int*)(ws + 65536);
  float*  gatev = (float*)(ws + 131072);
  ushort* dispb = (ushort*)(ws + 262144);                          // 32MB, reused as y
  ushort* wT    = (ushort*)(ws + 262144 + 33554432);               // 64MB (w1t then w2t)
  ushort* hbuf  = (ushort*)(ws + 262144 + 33554432 + 67108864);    // 128MB

  gate_kernel<<<NTOK / 4, 256, 0, stream>>>(x, wg, topi, gatev);
  scan_kernel<<<1, 256, 0, stream>>>(topi, pos);
  zero_kernel<<<2048, 256, 0, stream>>>((uint4*)dispb);
  scatter_kernel<<<NTOK / 4, 256, 0, stream>>>(x, topi, pos, dispb);

  // FFN layer 1: h = relu(disp @ w1 + b1)   [E,2048,1024]x[E,1024,4096]
  transpose_cvt<<<dim3(HDIM / 64, MDIM / 64, NEXP), 256, 0, stream>>>(w1, wT, MDIM, HDIM);
  gemm_bt<true, true><<<dim3(HDIM / 128, CAP / 128, NEXP), 256, 0, stream>>>(
      dispb, wT, b1, hbuf, CAP, HDIM, MDIM);

  // FFN layer 2: y = h @ w2 + b2            [E,2048,4096]x[E,4096,1024]
  transpose_cvt<<<dim3(MDIM / 64, HDIM / 64, NEXP), 256, 0, stream>>>(w2, wT, HDIM, MDIM);
  ushort* ybuf = dispb;  // dispb is dead after GEMM1
  gemm_bt<false, true><<<dim3(MDIM / 128, CAP / 128, NEXP), 256, 0, stream>>>(
      hbuf, wT, b2, ybuf, CAP, MDIM, HDIM);

  combine_kernel<<<NTOK / 4, 256, 0, stream>>>(ybuf, topi, pos, gatev, out);
}

// Round 2
// 553.770 us; speedup vs baseline: 1.0185x; 1.0185x over previous
//
#include <hip/hip_runtime.h>
#include <hip/hip_bf16.h>
#include <stdint.h>

#define NTOK 8192   // B*S
#define MDIM 1024
#define HDIM 4096
#define NEXP 8
#define CAP  2048   // int(1.0 * 2 * 8192 // 8)

typedef __attribute__((ext_vector_type(8))) short bf16x8;
typedef __attribute__((ext_vector_type(4))) float f32x4;

__device__ __forceinline__ ushort f2bf(float f) {
  uint32_t u = __builtin_bit_cast(uint32_t, f);
  u += 0x7FFFu + ((u >> 16) & 1u);          // round-to-nearest-even
  return (ushort)(u >> 16);
}
__device__ __forceinline__ float bf2f(ushort h) {
  uint32_t u = ((uint32_t)h) << 16;
  return __builtin_bit_cast(float, u);
}

// async global->LDS, 16B per lane; LDS dest = wave-uniform base + lane*16
#define GLOAD_LDS16(g, l)                                                    \
  __builtin_amdgcn_global_load_lds(                                          \
      (const __attribute__((address_space(1))) void*)(g),                    \
      (__attribute__((address_space(3))) void*)(l), 16, 0, 0)

// ---------------- gate: logits = x@wg (f64 accum), softmax-top2, normalize ----
__global__ __launch_bounds__(256) void gate_kernel(const float* __restrict__ x,
                                                   const float* __restrict__ wg,
                                                   int* __restrict__ topi,
                                                   float* __restrict__ gatev) {
  const int lane = threadIdx.x & 63;
  const int n = blockIdx.x * 4 + (threadIdx.x >> 6);   // one wave per token
  const float* xr = x + (size_t)n * MDIM;
  double acc[NEXP];
#pragma unroll
  for (int e = 0; e < NEXP; ++e) acc[e] = 0.0;
#pragma unroll
  for (int c = 0; c < 4; ++c) {
    float4 xv = *(const float4*)(xr + c * 256 + lane * 4);
    float xs[4] = {xv.x, xv.y, xv.z, xv.w};
#pragma unroll
    for (int j = 0; j < 4; ++j) {
      int m = c * 256 + lane * 4 + j;
      float4 w0 = *(const float4*)(wg + m * 8);
      float4 w1 = *(const float4*)(wg + m * 8 + 4);
      double xd = (double)xs[j];
      acc[0] += xd * (double)w0.x; acc[1] += xd * (double)w0.y;
      acc[2] += xd * (double)w0.z; acc[3] += xd * (double)w0.w;
      acc[4] += xd * (double)w1.x; acc[5] += xd * (double)w1.y;
      acc[6] += xd * (double)w1.z; acc[7] += xd * (double)w1.w;
    }
  }
#pragma unroll
  for (int off = 32; off >= 1; off >>= 1) {
#pragma unroll
    for (int e = 0; e < NEXP; ++e) acc[e] += __shfl_xor(acc[e], off, 64);
  }
  if (lane == 0) {
    int i0 = 0;
#pragma unroll
    for (int e = 1; e < NEXP; ++e) if (acc[e] > acc[i0]) i0 = e;
    int i1 = (i0 == 0) ? 1 : 0;
#pragma unroll
    for (int e = 0; e < NEXP; ++e) if (e != i0 && acc[e] > acc[i1]) i1 = e;
    // normalized top-2 of softmax == softmax over the two logits
    double e1 = exp(acc[i1] - acc[i0]);
    double s = 1.0 + e1;
    topi[n * 2 + 0] = i0; topi[n * 2 + 1] = i1;
    gatev[n * 2 + 0] = (float)(1.0 / s);
    gatev[n * 2 + 1] = (float)(e1 / s);
  }
}

// ---------------- slot-major cumulative positions (order: j = k*NTOK + n) ----
__global__ __launch_bounds__(256) void scan_kernel(const int* __restrict__ topi,
                                                   int* __restrict__ pos) {
  __shared__ int cnt[256][NEXP];
  const int t = threadIdx.x;
#pragma unroll
  for (int e = 0; e < NEXP; ++e) cnt[t][e] = 0;
  for (int i = 0; i < 64; ++i) {
    int j = t * 64 + i;
    int e = topi[(j & (NTOK - 1)) * 2 + (j >> 13)];
    cnt[t][e]++;
  }
  __syncthreads();
  if (t < NEXP) {          // exclusive scan over the 256 thread-chunks
    int run = 0;
    for (int i = 0; i < 256; ++i) { int v = cnt[i][t]; cnt[i][t] = run; run += v; }
  }
  __syncthreads();
  for (int i = 0; i < 64; ++i) {
    int j = t * 64 + i;
    int idx = (j & (NTOK - 1)) * 2 + (j >> 13);
    int e = topi[idx];
    pos[idx] = cnt[t][e]++;
  }
}

// ---------------- zero the dispatch buffer -----------------------------------
__global__ __launch_bounds__(256) void zero_kernel(uint4* __restrict__ p) {
  int t = blockIdx.x * 256 + threadIdx.x;
#pragma unroll
  for (int i = 0; i < 4; ++i) {
    uint4 z; z.x = 0; z.y = 0; z.z = 0; z.w = 0;
    p[t + i * 524288] = z;   // 2048 blocks * 256 thr * 4 * 16B = 32MB
  }
}

// ---------------- scatter x rows (bf16) into [E,CAP,M] -----------------------
__global__ __launch_bounds__(256) void scatter_kernel(const float* __restrict__ x,
                                                      const int* __restrict__ topi,
                                                      const int* __restrict__ pos,
                                                      ushort* __restrict__ disp) {
  const int lane = threadIdx.x & 63;
  const int n = blockIdx.x * 4 + (threadIdx.x >> 6);
  const float* src = x + (size_t)n * MDIM;
  ushort b[16];
#pragma unroll
  for (int c = 0; c < 4; ++c) {
    float4 v = *(const float4*)(src + c * 256 + lane * 4);
    b[c * 4 + 0] = f2bf(v.x); b[c * 4 + 1] = f2bf(v.y);
    b[c * 4 + 2] = f2bf(v.z); b[c * 4 + 3] = f2bf(v.w);
  }
#pragma unroll
  for (int k = 0; k < 2; ++k) {
    int p = pos[n * 2 + k];
    if (p < CAP) {
      int e = topi[n * 2 + k];
      ushort* dst = disp + ((size_t)(e * CAP + p)) * MDIM;
#pragma unroll
      for (int c = 0; c < 4; ++c) {
        ushort4 o; o.x = b[c*4+0]; o.y = b[c*4+1]; o.z = b[c*4+2]; o.w = b[c*4+3];
        *(ushort4*)(dst + c * 256 + lane * 4) = o;
      }
    }
  }
}

// ---------------- transpose + f32->bf16: in[R][C] -> out[C][R], per expert ---
__global__ __launch_bounds__(256) void transpose_cvt(const float* __restrict__ in,
                                                     ushort* __restrict__ out,
                                                     int R, int C) {
  __shared__ float tile[64][65];
  const int e = blockIdx.z;
  in  += (size_t)e * R * C;
  out += (size_t)e * R * C;
  const int r0 = blockIdx.y * 64, c0 = blockIdx.x * 64;
  const int t = threadIdx.x;
  const int r = t >> 2, cq = t & 3;
#pragma unroll
  for (int i = 0; i < 4; ++i) {
    float4 v = *(const float4*)(in + (size_t)(r0 + r) * C + c0 + cq * 16 + i * 4);
    tile[r][cq * 16 + i * 4 + 0] = v.x; tile[r][cq * 16 + i * 4 + 1] = v.y;
    tile[r][cq * 16 + i * 4 + 2] = v.z; tile[r][cq * 16 + i * 4 + 3] = v.w;
  }
  __syncthreads();
  const int oc = t >> 2, orr0 = (t & 3) * 16;
  ushort o16[16];
#pragma unroll
  for (int i = 0; i < 16; ++i) o16[i] = f2bf(tile[orr0 + i][oc]);
  ushort* dst = out + (size_t)(c0 + oc) * R + r0 + orr0;
  *(uint4*)dst = *(uint4*)&o16[0];
  *(uint4*)(dst + 8) = *(uint4*)&o16[8];
}

// ---------------- bf16 MFMA GEMM: C = A[M,K] * Bt[N,K]^T (+bias, relu) -------
// 128x128 tile, BK=64, 4 waves (2x2). global_load_lds(16B) staging with
// pre-swizzled SOURCE address (LDS dest stays linear, rule #21); XOR-swizzled
// ds_read_b128 fragments (conflict-free, verified round 1).
template <bool RELU, bool OUT_BF16>
__global__ __launch_bounds__(256) void gemm_bt(const ushort* __restrict__ A,
                                               const ushort* __restrict__ Bt,
                                               const float* __restrict__ bias,
                                               void* __restrict__ Cout,
                                               int Mrows, int Ncols, int Kdim) {
  __shared__ ushort As[128 * 64];
  __shared__ ushort Bs[128 * 64];
  const int e = blockIdx.z;
  A    += (size_t)e * Mrows * Kdim;
  Bt   += (size_t)e * Ncols * Kdim;
  bias += (size_t)e * Ncols;
  const size_t cbase = (size_t)e * Mrows * Ncols;
  const int m0 = blockIdx.y * 128, n0 = blockIdx.x * 128;
  const int t = threadIdx.x, lane = t & 63, w = t >> 6;
  const int wm = w >> 1, wn = w & 1;
  const int l15 = lane & 15, l4 = lane >> 4;

  // staging addresses: wave w stages rows [w*32, w*32+32) of each tile as
  // 4 segments of 8 rows. lane l covers row seg*8+(l>>3), LDS slot (l&7);
  // the GLOBAL chunk fetched is (l&7)^(l>>3) so LDS[r][c] = G[r][c^(r&7)].
  const int rs = lane >> 3, cc = lane & 7, cs = cc ^ rs;
  const ushort* aptr[4];
  const ushort* bptr[4];
  ushort* alds[4];
  ushort* blds[4];
#pragma unroll
  for (int s = 0; s < 4; ++s) {
    int row = w * 32 + s * 8 + rs;
    aptr[s] = A + (size_t)(m0 + row) * Kdim + cs * 8;
    bptr[s] = Bt + (size_t)(n0 + row) * Kdim + cs * 8;
    alds[s] = As + (w * 32 + s * 8) * 64;
    blds[s] = Bs + (w * 32 + s * 8) * 64;
  }

  f32x4 acc[4][4];
#pragma unroll
  for (int m = 0; m < 4; ++m)
#pragma unroll
    for (int n = 0; n < 4; ++n) acc[m][n] = (f32x4){0.f, 0.f, 0.f, 0.f};

  for (int k0 = 0; k0 < Kdim; k0 += 64) {
    __syncthreads();
#pragma unroll
    for (int s = 0; s < 4; ++s) {
      GLOAD_LDS16(aptr[s], alds[s]);
      GLOAD_LDS16(bptr[s], blds[s]);
      aptr[s] += 64;
      bptr[s] += 64;
    }
    __syncthreads();   // compiler emits vmcnt(0) drain before s_barrier
#pragma unroll
    for (int kk = 0; kk < 2; ++kk) {
      bf16x8 af[4], bfr[4];
#pragma unroll
      for (int m = 0; m < 4; ++m) {
        int row = wm * 64 + m * 16 + l15;
        af[m] = *(const bf16x8*)(As + row * 64 + (((kk * 4 + l4) ^ (row & 7)) * 8));
      }
#pragma unroll
      for (int n = 0; n < 4; ++n) {
        int row = wn * 64 + n * 16 + l15;
        bfr[n] = *(const bf16x8*)(Bs + row * 64 + (((kk * 4 + l4) ^ (row & 7)) * 8));
      }
#pragma unroll
      for (int m = 0; m < 4; ++m)
#pragma unroll
        for (int n = 0; n < 4; ++n)
          acc[m][n] = __builtin_amdgcn_mfma_f32_16x16x32_bf16(af[m], bfr[n], acc[m][n], 0, 0, 0);
    }
  }
  // epilogue: D[row=(l>>4)*4+r][col=l&15]
#pragma unroll
  for (int n = 0; n < 4; ++n) {
    int col = n0 + wn * 64 + n * 16 + l15;
    float bv = bias[col];
#pragma unroll
    for (int m = 0; m < 4; ++m) {
      int rowb = m0 + wm * 64 + m * 16 + l4 * 4;
#pragma unroll
      for (int r = 0; r < 4; ++r) {
        float v = acc[m][n][r] + bv;
        if (RELU) v = fmaxf(v, 0.f);
        size_t oidx = cbase + (size_t)(rowb + r) * Ncols + col;
        if (OUT_BF16) ((ushort*)Cout)[oidx] = f2bf(v);
        else          ((float*)Cout)[oidx] = v;
      }
    }
  }
}

// ---------------- combine: out[n] = sum_k gate * y[e_k, p_k] -----------------
__global__ __launch_bounds__(256) void combine_kernel(const ushort* __restrict__ y,
                                                      const int* __restrict__ topi,
                                                      const int* __restrict__ pos,
                                                      const float* __restrict__ gatev,
                                                      float* __restrict__ out) {
  const int lane = threadIdx.x & 63;
  const int n = blockIdx.x * 4 + (threadIdx.x >> 6);
  int i0 = topi[n * 2], i1 = topi[n * 2 + 1];
  int p0 = pos[n * 2], p1 = pos[n * 2 + 1];
  float g0 = (p0 < CAP) ? gatev[n * 2] : 0.f;
  float g1 = (p1 < CAP) ? gatev[n * 2 + 1] : 0.f;
  const ushort* y0 = y + (size_t)(i0 * CAP + (p0 < CAP ? p0 : 0)) * MDIM;
  const ushort* y1 = y + (size_t)(i1 * CAP + (p1 < CAP ? p1 : 0)) * MDIM;
  float* o = out + (size_t)n * MDIM;
#pragma unroll
  for (int c = 0; c < 4; ++c) {
    int idx = c * 256 + lane * 4;
    ushort4 a = *(const ushort4*)(y0 + idx);
    ushort4 b = *(const ushort4*)(y1 + idx);
    float4 ov;
    ov.x = g0 * bf2f(a.x) + g1 * bf2f(b.x);
    ov.y = g0 * bf2f(a.y) + g1 * bf2f(b.y);
    ov.z = g0 * bf2f(a.z) + g1 * bf2f(b.z);
    ov.w = g0 * bf2f(a.w) + g1 * bf2f(b.w);
    *(float4*)(o + idx) = ov;
  }
}

extern "C" void kernel_launch(void* const* d_in, const int* in_sizes, int n_in,
                              void* d_out, int out_size, void* d_ws, size_t ws_size,
                              hipStream_t stream) {
  const float* x  = (const float*)d_in[0];
  const float* wg = (const float*)d_in[1];
  const float* w1 = (const float*)d_in[2];
  const float* b1 = (const float*)d_in[3];
  const float* w2 = (const float*)d_in[4];
  const float* b2 = (const float*)d_in[5];
  float* out = (float*)d_out;
  char* ws = (char*)d_ws;

  // workspace layout (224.3 MB total)
  int*    topi  = (int*)(ws);
  int*    pos   = (int*)(ws + 65536);
  float*  gatev = (float*)(ws + 131072);
  ushort* dispb = (ushort*)(ws + 262144);                          // 32MB, reused as y
  ushort* wT    = (ushort*)(ws + 262144 + 33554432);               // 64MB (w1t then w2t)
  ushort* hbuf  = (ushort*)(ws + 262144 + 33554432 + 67108864);    // 128MB

  gate_kernel<<<NTOK / 4, 256, 0, stream>>>(x, wg, topi, gatev);
  scan_kernel<<<1, 256, 0, stream>>>(topi, pos);
  zero_kernel<<<2048, 256, 0, stream>>>((uint4*)dispb);
  scatter_kernel<<<NTOK / 4, 256, 0, stream>>>(x, topi, pos, dispb);

  // FFN layer 1: h = relu(disp @ w1 + b1)   [E,2048,1024]x[E,1024,4096]
  transpose_cvt<<<dim3(HDIM / 64, MDIM / 64, NEXP), 256, 0, stream>>>(w1, wT, MDIM, HDIM);
  gemm_bt<true, true><<<dim3(HDIM / 128, CAP / 128, NEXP), 256, 0, stream>>>(
      dispb, wT, b1, hbuf, CAP, HDIM, MDIM);

  // FFN layer 2: y = h @ w2 + b2            [E,2048,4096]x[E,4096,1024]
  transpose_cvt<<<dim3(MDIM / 64, HDIM / 64, NEXP), 256, 0, stream>>>(w2, wT, HDIM, MDIM);
  ushort* ybuf = dispb;  // dispb is dead after GEMM1
  gemm_bt<false, true><<<dim3(MDIM / 128, CAP / 128, NEXP), 256, 0, stream>>>(
      hbuf, wT, b2, ybuf, CAP, MDIM, HDIM);

  combine_kernel<<<NTOK / 4, 256, 0, stream>>>(ybuf, topi, pos, gatev, out);
}

// Round 3
// 451.484 us; speedup vs baseline: 1.2493x; 1.2266x over previous
//
#include <hip/hip_runtime.h>
#include <hip/hip_bf16.h>
#include <stdint.h>

#define NTOK 8192   // B*S
#define MDIM 1024
#define HDIM 4096
#define NEXP 8
#define CAP  2048   // int(1.0 * 2 * 8192 // 8)

typedef __attribute__((ext_vector_type(8))) short bf16x8;
typedef __attribute__((ext_vector_type(4))) float f32x4;

__device__ __forceinline__ ushort f2bf(float f) {
  uint32_t u = __builtin_bit_cast(uint32_t, f);
  u += 0x7FFFu + ((u >> 16) & 1u);          // round-to-nearest-even
  return (ushort)(u >> 16);
}
__device__ __forceinline__ float bf2f(ushort h) {
  uint32_t u = ((uint32_t)h) << 16;
  return __builtin_bit_cast(float, u);
}

// async global->LDS, 16B per lane; LDS dest = wave-uniform base + lane*16
#define GLOAD_LDS16(g, l)                                                    \
  __builtin_amdgcn_global_load_lds(                                          \
      (const __attribute__((address_space(1))) void*)(g),                    \
      (__attribute__((address_space(3))) void*)(l), 16, 0, 0)

// ---------------- gate: logits = x@wg (f64 accum), softmax-top2, normalize ----
__global__ __launch_bounds__(256) void gate_kernel(const float* __restrict__ x,
                                                   const float* __restrict__ wg,
                                                   int* __restrict__ topi,
                                                   float* __restrict__ gatev) {
  const int lane = threadIdx.x & 63;
  const int n = blockIdx.x * 4 + (threadIdx.x >> 6);   // one wave per token
  const float* xr = x + (size_t)n * MDIM;
  double acc[NEXP];
#pragma unroll
  for (int e = 0; e < NEXP; ++e) acc[e] = 0.0;
#pragma unroll
  for (int c = 0; c < 4; ++c) {
    float4 xv = *(const float4*)(xr + c * 256 + lane * 4);
    float xs[4] = {xv.x, xv.y, xv.z, xv.w};
#pragma unroll
    for (int j = 0; j < 4; ++j) {
      int m = c * 256 + lane * 4 + j;
      float4 w0 = *(const float4*)(wg + m * 8);
      float4 w1 = *(const float4*)(wg + m * 8 + 4);
      double xd = (double)xs[j];
      acc[0] += xd * (double)w0.x; acc[1] += xd * (double)w0.y;
      acc[2] += xd * (double)w0.z; acc[3] += xd * (double)w0.w;
      acc[4] += xd * (double)w1.x; acc[5] += xd * (double)w1.y;
      acc[6] += xd * (double)w1.z; acc[7] += xd * (double)w1.w;
    }
  }
#pragma unroll
  for (int off = 32; off >= 1; off >>= 1) {
#pragma unroll
    for (int e = 0; e < NEXP; ++e) acc[e] += __shfl_xor(acc[e], off, 64);
  }
  if (lane == 0) {
    int i0 = 0;
#pragma unroll
    for (int e = 1; e < NEXP; ++e) if (acc[e] > acc[i0]) i0 = e;
    int i1 = (i0 == 0) ? 1 : 0;
#pragma unroll
    for (int e = 0; e < NEXP; ++e) if (e != i0 && acc[e] > acc[i1]) i1 = e;
    // normalized top-2 of softmax == softmax over the two logits
    double e1 = exp(acc[i1] - acc[i0]);
    double s = 1.0 + e1;
    topi[n * 2 + 0] = i0; topi[n * 2 + 1] = i1;
    gatev[n * 2 + 0] = (float)(1.0 / s);
    gatev[n * 2 + 1] = (float)(e1 / s);
  }
}

// ---------------- slot-major cumulative positions (order: j = k*NTOK + n) ----
__global__ __launch_bounds__(256) void scan_kernel(const int* __restrict__ topi,
                                                   int* __restrict__ pos) {
  __shared__ int cnt[256][NEXP];
  const int t = threadIdx.x;
#pragma unroll
  for (int e = 0; e < NEXP; ++e) cnt[t][e] = 0;
  for (int i = 0; i < 64; ++i) {
    int j = t * 64 + i;
    int e = topi[(j & (NTOK - 1)) * 2 + (j >> 13)];
    cnt[t][e]++;
  }
  __syncthreads();
  if (t < NEXP) {          // exclusive scan over the 256 thread-chunks
    int run = 0;
    for (int i = 0; i < 256; ++i) { int v = cnt[i][t]; cnt[i][t] = run; run += v; }
  }
  __syncthreads();
  for (int i = 0; i < 64; ++i) {
    int j = t * 64 + i;
    int idx = (j & (NTOK - 1)) * 2 + (j >> 13);
    int e = topi[idx];
    pos[idx] = cnt[t][e]++;
  }
}

// ---------------- zero the dispatch buffer -----------------------------------
__global__ __launch_bounds__(256) void zero_kernel(uint4* __restrict__ p) {
  int t = blockIdx.x * 256 + threadIdx.x;
#pragma unroll
  for (int i = 0; i < 4; ++i) {
    uint4 z; z.x = 0; z.y = 0; z.z = 0; z.w = 0;
    p[t + i * 524288] = z;   // 2048 blocks * 256 thr * 4 * 16B = 32MB
  }
}

// ---------------- scatter x rows (bf16) into [E,CAP,M] -----------------------
__global__ __launch_bounds__(256) void scatter_kernel(const float* __restrict__ x,
                                                      const int* __restrict__ topi,
                                                      const int* __restrict__ pos,
                                                      ushort* __restrict__ disp) {
  const int lane = threadIdx.x & 63;
  const int n = blockIdx.x * 4 + (threadIdx.x >> 6);
  const float* src = x + (size_t)n * MDIM;
  ushort b[16];
#pragma unroll
  for (int c = 0; c < 4; ++c) {
    float4 v = *(const float4*)(src + c * 256 + lane * 4);
    b[c * 4 + 0] = f2bf(v.x); b[c * 4 + 1] = f2bf(v.y);
    b[c * 4 + 2] = f2bf(v.z); b[c * 4 + 3] = f2bf(v.w);
  }
#pragma unroll
  for (int k = 0; k < 2; ++k) {
    int p = pos[n * 2 + k];
    if (p < CAP) {
      int e = topi[n * 2 + k];
      ushort* dst = disp + ((size_t)(e * CAP + p)) * MDIM;
#pragma unroll
      for (int c = 0; c < 4; ++c) {
        ushort4 o; o.x = b[c*4+0]; o.y = b[c*4+1]; o.z = b[c*4+2]; o.w = b[c*4+3];
        *(ushort4*)(dst + c * 256 + lane * 4) = o;
      }
    }
  }
}

// ---------------- transpose + f32->bf16: in[R][C] -> out[C][R], per expert ---
__global__ __launch_bounds__(256) void transpose_cvt(const float* __restrict__ in,
                                                     ushort* __restrict__ out,
                                                     int R, int C) {
  __shared__ float tile[64][65];
  const int e = blockIdx.z;
  in  += (size_t)e * R * C;
  out += (size_t)e * R * C;
  const int r0 = blockIdx.y * 64, c0 = blockIdx.x * 64;
  const int t = threadIdx.x;
  const int r = t >> 2, cq = t & 3;
#pragma unroll
  for (int i = 0; i < 4; ++i) {
    float4 v = *(const float4*)(in + (size_t)(r0 + r) * C + c0 + cq * 16 + i * 4);
    tile[r][cq * 16 + i * 4 + 0] = v.x; tile[r][cq * 16 + i * 4 + 1] = v.y;
    tile[r][cq * 16 + i * 4 + 2] = v.z; tile[r][cq * 16 + i * 4 + 3] = v.w;
  }
  __syncthreads();
  const int oc = t >> 2, orr0 = (t & 3) * 16;
  ushort o16[16];
#pragma unroll
  for (int i = 0; i < 16; ++i) o16[i] = f2bf(tile[orr0 + i][oc]);
  ushort* dst = out + (size_t)(c0 + oc) * R + r0 + orr0;
  *(uint4*)dst = *(uint4*)&o16[0];
  *(uint4*)(dst + 8) = *(uint4*)&o16[8];
}

// ============================================================================
// 256x256x64 8-phase bf16 GEMM (m201 template, plain HIP):
//   C[M,N] = A[M,K] * Bt[N,K]^T (+bias, optional relu), bf16 out.
// 512 thr = 8 waves. LDS 128KB: A[d][half][128][64], B[d][half][128][64],
// XOR-swizzled rows (LDS[r][c] = G[r][c^(r&7)], 16B chunks) staged via
// global_load_lds(16B) with pre-swizzled source. Quadrant order per tile:
// q0=(A0,B0) q1=(A0,B1) q2=(A1,B1) q3=(A1,B0); half-stage issue order
// A0,B1,A1,B0 at slot = phase+6; vmcnt(4) only at phases 4/8 (counted,
// never 0 in main loop). Sync ledger verified: every stage targets a
// region dead since the previous barrier; every read covered by the
// preceding vmcnt(4)+barrier.
// ============================================================================
template <bool RELU>
__global__ __launch_bounds__(512, 2) void gemm8p(const ushort* __restrict__ Ag,
                                                 const ushort* __restrict__ Btg,
                                                 const float* __restrict__ biasg,
                                                 ushort* __restrict__ Cout,
                                                 int Mrows, int Ncols, int Kdim) {
  __shared__ ushort sh[65536];   // 128 KiB
  // bijective XCD swizzle (grids are %8==0)
  const int gx = gridDim.x, gy = gridDim.y;
  const int nwg = gx * gy * gridDim.z;
  const int lin = blockIdx.x + gx * (blockIdx.y + gy * blockIdx.z);
  const int cpx = nwg >> 3;
  const int swz = (lin & 7) * cpx + (lin >> 3);
  const int gxy = gx * gy;
  const int ez = swz / gxy;
  const int rem = swz - ez * gxy;
  const int by = rem / gx;
  const int bx = rem - by * gx;

  const ushort* A  = Ag  + (size_t)ez * Mrows * Kdim;
  const ushort* Bt = Btg + (size_t)ez * Ncols * Kdim;
  const float* bias = biasg + (size_t)ez * Ncols;
  ushort* Cptr = Cout + (size_t)ez * Mrows * Ncols;
  const int m0 = by * 256, n0 = bx * 256;
  const int t = threadIdx.x, lane = t & 63, w = t >> 6;
  const int l15 = lane & 15, l4 = lane >> 4;
  const int wr = w >> 2, wc = w & 3;      // 2x4 wave grid over quadrant frags

  // ---- staging addressing (verified round-2 pattern) ----
  const int srow = lane >> 3;             // 0..7 row within 8-row slab
  const int cs = (lane & 7) ^ srow;       // pre-swizzled source chunk
  const ushort* Abase = A  + (size_t)(m0 + w * 8 + srow) * Kdim + cs * 8;
  const ushort* Bbase = Bt + (size_t)(n0 + w * 8 + srow) * Kdim + cs * 8;
  const int ldsw = w * 512;               // wave-uniform LDS offset (ushorts)

  // stage one half (128 rows x 64 K-cols = 16KB) of A or B: 2 gloads/thread
#define STAGE8(isA, d, half, ktile)                                          \
  do {                                                                       \
    const ushort* gb = ((isA) ? Abase : Bbase) +                             \
                       (size_t)((half) * 128) * Kdim + (ktile) * 64;         \
    ushort* lb = sh + ((isA) ? 0 : 32768) + ((d) * 2 + (half)) * 8192 + ldsw;\
    GLOAD_LDS16(gb, lb);                                                     \
    GLOAD_LDS16(gb + (size_t)64 * Kdim, lb + 4096);                         \
  } while (0)

  // ---- fragment-read addressing ----
  const int chk0 = ((0 + l4) ^ (l15 & 7)) * 8;   // kk=0 chunk (ushorts)
  const int chk1 = ((4 + l4) ^ (l15 & 7)) * 8;   // kk=1 chunk
  const int aoff = (wr * 64 + l15) * 64;
  const int boff = (wc * 32 + l15) * 64;

  f32x4 acc[8][4];
#pragma unroll
  for (int i = 0; i < 8; ++i)
#pragma unroll
    for (int j = 0; j < 4; ++j) acc[i][j] = (f32x4){0.f, 0.f, 0.f, 0.f};

#define PHASE8(d, ai, bj, DO_STAGE, SA, SD, SH, ST, DO_WAIT)                 \
  {                                                                          \
    __builtin_amdgcn_sched_barrier(0);                                       \
    const ushort* Ar = sh + ((d) * 2 + (ai)) * 8192 + aoff;                  \
    const ushort* Br = sh + 32768 + ((d) * 2 + (bj)) * 8192 + boff;          \
    bf16x8 af0[4], af1[4], bf0[2], bf1[2];                                   \
    _Pragma("unroll") for (int fr = 0; fr < 4; ++fr) {                       \
      af0[fr] = *(const bf16x8*)(Ar + fr * 1024 + chk0);                     \
      af1[fr] = *(const bf16x8*)(Ar + fr * 1024 + chk1);                     \
    }                                                                        \
    _Pragma("unroll") for (int fc = 0; fc < 2; ++fc) {                       \
      bf0[fc] = *(const bf16x8*)(Br + fc * 1024 + chk0);                     \
      bf1[fc] = *(const bf16x8*)(Br + fc * 1024 + chk1);                     \
    }                                                                        \
    if (DO_STAGE) STAGE8(SA, SD, SH, ST);                                    \
    __builtin_amdgcn_sched_barrier(0);                                       \
    __builtin_amdgcn_s_barrier();                                            \
    __builtin_amdgcn_s_setprio(1);                                           \
    _Pragma("unroll") for (int fr = 0; fr < 4; ++fr)                         \
      _Pragma("unroll") for (int fc = 0; fc < 2; ++fc) {                     \
        acc[(ai) * 4 + fr][(bj) * 2 + fc] =                                  \
            __builtin_amdgcn_mfma_f32_16x16x32_bf16(                         \
                af0[fr], bf0[fc], acc[(ai) * 4 + fr][(bj) * 2 + fc], 0, 0, 0);\
        acc[(ai) * 4 + fr][(bj) * 2 + fc] =                                  \
            __builtin_amdgcn_mfma_f32_16x16x32_bf16(                         \
                af1[fr], bf1[fc], acc[(ai) * 4 + fr][(bj) * 2 + fc], 0, 0, 0);\
      }                                                                      \
    __builtin_amdgcn_s_setprio(0);                                           \
    __builtin_amdgcn_sched_barrier(0);                                       \
    if (DO_WAIT) { asm volatile("s_waitcnt vmcnt(4)" ::: "memory"); }        \
    __builtin_amdgcn_s_barrier();                                            \
  }

  const int NT = Kdim >> 6;
  // prologue: slots 0..5 = (t0:A0,B1,A1,B0) (t1:A0,B1); wait so tile0 ready
  STAGE8(1, 0, 0, 0);
  STAGE8(0, 0, 1, 0);
  STAGE8(1, 0, 1, 0);
  STAGE8(0, 0, 0, 0);
  STAGE8(1, 1, 0, 1);
  STAGE8(0, 1, 1, 1);
  asm volatile("s_waitcnt vmcnt(4)" ::: "memory");
  __builtin_amdgcn_sched_barrier(0);
  __builtin_amdgcn_s_barrier();

  for (int t2 = 0; t2 < (NT >> 1); ++t2) {
    const int tb = 2 * t2;
    const bool g2 = (tb + 2) < NT, g3 = (tb + 3) < NT;
    // tile tb (buf0):
    PHASE8(0, 0, 0, true, 1, 1, 1, tb + 1, 0)   // q0; stage A1 of t(b+1)->buf1
    PHASE8(0, 0, 1, true, 0, 1, 0, tb + 1, 0)   // q1; stage B0 of t(b+1)->buf1
    PHASE8(0, 1, 1, g2,   1, 0, 0, tb + 2, 0)   // q2; stage A0 of t(b+2)->buf0
    PHASE8(0, 1, 0, g2,   0, 0, 1, tb + 2, 1)   // q3; stage B1; vmcnt(4)
    // tile tb+1 (buf1):
    PHASE8(1, 0, 0, g2,   1, 0, 1, tb + 2, 0)   // q0; stage A1 of t(b+2)->buf0
    PHASE8(1, 0, 1, g2,   0, 0, 0, tb + 2, 0)   // q1; stage B0 of t(b+2)->buf0
    PHASE8(1, 1, 1, g3,   1, 1, 0, tb + 3, 0)   // q2; stage A0 of t(b+3)->buf1
    PHASE8(1, 1, 0, g3,   0, 1, 1, tb + 3, 1)   // q3; stage B1; vmcnt(4)
  }

  // epilogue: D[row=(l>>4)*4+r][col=l&15] per 16x16 frag
#pragma unroll
  for (int ai = 0; ai < 2; ++ai)
#pragma unroll
    for (int fr = 0; fr < 4; ++fr) {
      const int rowb = m0 + ai * 128 + wr * 64 + fr * 16 + l4 * 4;
#pragma unroll
      for (int bj = 0; bj < 2; ++bj)
#pragma unroll
        for (int fc = 0; fc < 2; ++fc) {
          const int col = n0 + bj * 128 + wc * 32 + fc * 16 + l15;
          const float bv = bias[col];
          f32x4 v = acc[ai * 4 + fr][bj * 2 + fc];
#pragma unroll
          for (int r = 0; r < 4; ++r) {
            float f = v[r] + bv;
            if (RELU) f = fmaxf(f, 0.f);
            Cptr[(size_t)(rowb + r) * Ncols + col] = f2bf(f);
          }
        }
    }
#undef PHASE8
#undef STAGE8
}

// ---------------- combine: out[n] = sum_k gate * y[e_k, p_k] -----------------
__global__ __launch_bounds__(256) void combine_kernel(const ushort* __restrict__ y,
                                                      const int* __restrict__ topi,
                                                      const int* __restrict__ pos,
                                                      const float* __restrict__ gatev,
                                                      float* __restrict__ out) {
  const int lane = threadIdx.x & 63;
  const int n = blockIdx.x * 4 + (threadIdx.x >> 6);
  int i0 = topi[n * 2], i1 = topi[n * 2 + 1];
  int p0 = pos[n * 2], p1 = pos[n * 2 + 1];
  float g0 = (p0 < CAP) ? gatev[n * 2] : 0.f;
  float g1 = (p1 < CAP) ? gatev[n * 2 + 1] : 0.f;
  const ushort* y0 = y + (size_t)(i0 * CAP + (p0 < CAP ? p0 : 0)) * MDIM;
  const ushort* y1 = y + (size_t)(i1 * CAP + (p1 < CAP ? p1 : 0)) * MDIM;
  float* o = out + (size_t)n * MDIM;
#pragma unroll
  for (int c = 0; c < 4; ++c) {
    int idx = c * 256 + lane * 4;
    ushort4 a = *(const ushort4*)(y0 + idx);
    ushort4 b = *(const ushort4*)(y1 + idx);
    float4 ov;
    ov.x = g0 * bf2f(a.x) + g1 * bf2f(b.x);
    ov.y = g0 * bf2f(a.y) + g1 * bf2f(b.y);
    ov.z = g0 * bf2f(a.z) + g1 * bf2f(b.z);
    ov.w = g0 * bf2f(a.w) + g1 * bf2f(b.w);
    *(float4*)(o + idx) = ov;
  }
}

extern "C" void kernel_launch(void* const* d_in, const int* in_sizes, int n_in,
                              void* d_out, int out_size, void* d_ws, size_t ws_size,
                              hipStream_t stream) {
  const float* x  = (const float*)d_in[0];
  const float* wg = (const float*)d_in[1];
  const float* w1 = (const float*)d_in[2];
  const float* b1 = (const float*)d_in[3];
  const float* w2 = (const float*)d_in[4];
  const float* b2 = (const float*)d_in[5];
  float* out = (float*)d_out;
  char* ws = (char*)d_ws;

  // workspace layout (224.3 MB total)
  int*    topi  = (int*)(ws);
  int*    pos   = (int*)(ws + 65536);
  float*  gatev = (float*)(ws + 131072);
  ushort* dispb = (ushort*)(ws + 262144);                          // 32MB, reused as y
  ushort* wT    = (ushort*)(ws + 262144 + 33554432);               // 64MB (w1t then w2t)
  ushort* hbuf  = (ushort*)(ws + 262144 + 33554432 + 67108864);    // 128MB

  gate_kernel<<<NTOK / 4, 256, 0, stream>>>(x, wg, topi, gatev);
  scan_kernel<<<1, 256, 0, stream>>>(topi, pos);
  zero_kernel<<<2048, 256, 0, stream>>>((uint4*)dispb);
  scatter_kernel<<<NTOK / 4, 256, 0, stream>>>(x, topi, pos, dispb);

  // FFN layer 1: h = relu(disp @ w1 + b1)   [E,2048,1024]x[E,1024,4096]
  transpose_cvt<<<dim3(HDIM / 64, MDIM / 64, NEXP), 256, 0, stream>>>(w1, wT, MDIM, HDIM);
  gemm8p<true><<<dim3(HDIM / 256, CAP / 256, NEXP), 512, 0, stream>>>(
      dispb, wT, b1, hbuf, CAP, HDIM, MDIM);

  // FFN layer 2: y = h @ w2 + b2            [E,2048,4096]x[E,4096,1024]
  transpose_cvt<<<dim3(MDIM / 64, HDIM / 64, NEXP), 256, 0, stream>>>(w2, wT, HDIM, MDIM);
  ushort* ybuf = dispb;  // dispb is dead after GEMM1
  gemm8p<false><<<dim3(MDIM / 256, CAP / 256, NEXP), 512, 0, stream>>>(
      hbuf, wT, b2, ybuf, CAP, MDIM, HDIM);

  combine_kernel<<<NTOK / 4, 256, 0, stream>>>(ybuf, topi, pos, gatev, out);
}

// Round 4
// 422.919 us; speedup vs baseline: 1.3337x; 1.0675x over previous
//
#include <hip/hip_runtime.h>
#include <hip/hip_bf16.h>
#include <stdint.h>

#define NTOK 8192   // B*S
#define MDIM 1024
#define HDIM 4096
#define NEXP 8
#define CAP  2048   // int(1.0 * 2 * 8192 // 8)

typedef __attribute__((ext_vector_type(8))) short bf16x8;
typedef __attribute__((ext_vector_type(4))) float f32x4;

__device__ __forceinline__ ushort f2bf(float f) {
  uint32_t u = __builtin_bit_cast(uint32_t, f);
  u += 0x7FFFu + ((u >> 16) & 1u);          // round-to-nearest-even
  return (ushort)(u >> 16);
}
__device__ __forceinline__ float bf2f(ushort h) {
  uint32_t u = ((uint32_t)h) << 16;
  return __builtin_bit_cast(float, u);
}

// async global->LDS, 16B per lane; LDS dest = wave-uniform base + lane*16
#define GLOAD_LDS16(g, l)                                                    \
  __builtin_amdgcn_global_load_lds(                                          \
      (const __attribute__((address_space(1))) void*)(g),                    \
      (__attribute__((address_space(3))) void*)(l), 16, 0, 0)

// ---------------- gate: logits = x@wg (f64 accum), softmax-top2, normalize ----
__global__ __launch_bounds__(256) void gate_kernel(const float* __restrict__ x,
                                                   const float* __restrict__ wg,
                                                   int* __restrict__ topi,
                                                   float* __restrict__ gatev) {
  const int lane = threadIdx.x & 63;
  const int n = blockIdx.x * 4 + (threadIdx.x >> 6);   // one wave per token
  const float* xr = x + (size_t)n * MDIM;
  double acc[NEXP];
#pragma unroll
  for (int e = 0; e < NEXP; ++e) acc[e] = 0.0;
#pragma unroll
  for (int c = 0; c < 4; ++c) {
    float4 xv = *(const float4*)(xr + c * 256 + lane * 4);
    float xs[4] = {xv.x, xv.y, xv.z, xv.w};
#pragma unroll
    for (int j = 0; j < 4; ++j) {
      int m = c * 256 + lane * 4 + j;
      float4 w0 = *(const float4*)(wg + m * 8);
      float4 w1 = *(const float4*)(wg + m * 8 + 4);
      double xd = (double)xs[j];
      acc[0] += xd * (double)w0.x; acc[1] += xd * (double)w0.y;
      acc[2] += xd * (double)w0.z; acc[3] += xd * (double)w0.w;
      acc[4] += xd * (double)w1.x; acc[5] += xd * (double)w1.y;
      acc[6] += xd * (double)w1.z; acc[7] += xd * (double)w1.w;
    }
  }
#pragma unroll
  for (int off = 32; off >= 1; off >>= 1) {
#pragma unroll
    for (int e = 0; e < NEXP; ++e) acc[e] += __shfl_xor(acc[e], off, 64);
  }
  if (lane == 0) {
    int i0 = 0;
#pragma unroll
    for (int e = 1; e < NEXP; ++e) if (acc[e] > acc[i0]) i0 = e;
    int i1 = (i0 == 0) ? 1 : 0;
#pragma unroll
    for (int e = 0; e < NEXP; ++e) if (e != i0 && acc[e] > acc[i1]) i1 = e;
    // normalized top-2 of softmax == softmax over the two logits
    double e1 = exp(acc[i1] - acc[i0]);
    double s = 1.0 + e1;
    topi[n * 2 + 0] = i0; topi[n * 2 + 1] = i1;
    gatev[n * 2 + 0] = (float)(1.0 / s);
    gatev[n * 2 + 1] = (float)(e1 / s);
  }
}

// ---------------- slot-major cumulative positions (order: j = k*NTOK + n) ----
__global__ __launch_bounds__(256) void scan_kernel(const int* __restrict__ topi,
                                                   int* __restrict__ pos) {
  __shared__ int cnt[256][NEXP];
  const int t = threadIdx.x;
#pragma unroll
  for (int e = 0; e < NEXP; ++e) cnt[t][e] = 0;
  for (int i = 0; i < 64; ++i) {
    int j = t * 64 + i;
    int e = topi[(j & (NTOK - 1)) * 2 + (j >> 13)];
    cnt[t][e]++;
  }
  __syncthreads();
  if (t < NEXP) {          // exclusive scan over the 256 thread-chunks
    int run = 0;
    for (int i = 0; i < 256; ++i) { int v = cnt[i][t]; cnt[i][t] = run; run += v; }
  }
  __syncthreads();
  for (int i = 0; i < 64; ++i) {
    int j = t * 64 + i;
    int idx = (j & (NTOK - 1)) * 2 + (j >> 13);
    int e = topi[idx];
    pos[idx] = cnt[t][e]++;
  }
}

// ---------------- zero the dispatch buffer -----------------------------------
__global__ __launch_bounds__(256) void zero_kernel(uint4* __restrict__ p) {
  int t = blockIdx.x * 256 + threadIdx.x;
#pragma unroll
  for (int i = 0; i < 4; ++i) {
    uint4 z; z.x = 0; z.y = 0; z.z = 0; z.w = 0;
    p[t + i * 524288] = z;   // 2048 blocks * 256 thr * 4 * 16B = 32MB
  }
}

// ---------------- scatter x rows (bf16) into [E,CAP,M] -----------------------
__global__ __launch_bounds__(256) void scatter_kernel(const float* __restrict__ x,
                                                      const int* __restrict__ topi,
                                                      const int* __restrict__ pos,
                                                      ushort* __restrict__ disp) {
  const int lane = threadIdx.x & 63;
  const int n = blockIdx.x * 4 + (threadIdx.x >> 6);
  const float* src = x + (size_t)n * MDIM;
  ushort b[16];
#pragma unroll
  for (int c = 0; c < 4; ++c) {
    float4 v = *(const float4*)(src + c * 256 + lane * 4);
    b[c * 4 + 0] = f2bf(v.x); b[c * 4 + 1] = f2bf(v.y);
    b[c * 4 + 2] = f2bf(v.z); b[c * 4 + 3] = f2bf(v.w);
  }
#pragma unroll
  for (int k = 0; k < 2; ++k) {
    int p = pos[n * 2 + k];
    if (p < CAP) {
      int e = topi[n * 2 + k];
      ushort* dst = disp + ((size_t)(e * CAP + p)) * MDIM;
#pragma unroll
      for (int c = 0; c < 4; ++c) {
        ushort4 o; o.x = b[c*4+0]; o.y = b[c*4+1]; o.z = b[c*4+2]; o.w = b[c*4+3];
        *(ushort4*)(dst + c * 256 + lane * 4) = o;
      }
    }
  }
}

// ---------------- transpose + f32->bf16: in[R][C] -> out[C][R], per expert ---
__global__ __launch_bounds__(256) void transpose_cvt(const float* __restrict__ in,
                                                     ushort* __restrict__ out,
                                                     int R, int C) {
  __shared__ float tile[64][65];
  const int e = blockIdx.z;
  in  += (size_t)e * R * C;
  out += (size_t)e * R * C;
  const int r0 = blockIdx.y * 64, c0 = blockIdx.x * 64;
  const int t = threadIdx.x;
  const int r = t >> 2, cq = t & 3;
#pragma unroll
  for (int i = 0; i < 4; ++i) {
    float4 v = *(const float4*)(in + (size_t)(r0 + r) * C + c0 + cq * 16 + i * 4);
    tile[r][cq * 16 + i * 4 + 0] = v.x; tile[r][cq * 16 + i * 4 + 1] = v.y;
    tile[r][cq * 16 + i * 4 + 2] = v.z; tile[r][cq * 16 + i * 4 + 3] = v.w;
  }
  __syncthreads();
  const int oc = t >> 2, orr0 = (t & 3) * 16;
  ushort o16[16];
#pragma unroll
  for (int i = 0; i < 16; ++i) o16[i] = f2bf(tile[orr0 + i][oc]);
  ushort* dst = out + (size_t)(c0 + oc) * R + r0 + orr0;
  *(uint4*)dst = *(uint4*)&o16[0];
  *(uint4*)(dst + 8) = *(uint4*)&o16[8];
}

// ============================================================================
// 256x256x64 8-phase bf16 GEMM (m201 template) with register fragment reuse:
// per K-tile quadrant walk q0=(A0,B0) q1=(A0,B1) q2=(A1,B1) q3=(A1,B0);
// A-frags held across phase pairs, B0 held q0->q3 => 24 ds_read_b128/tile/wave
// (was 48 in round 3 -> LDS pipe capped MfmaUtil at ~34%).
// Staging: global_load_lds(16B), pre-swizzled source, linear LDS dest;
// counted vmcnt(4) at phases 4/8; vmcnt(0) at last iter's phase 4 (tail-race
// fix: only 8 loads outstanding there, vmcnt(4) would not cover A1/B0).
// ============================================================================
template <bool RELU>
__global__ __launch_bounds__(512, 1) void gemm8p(const ushort* __restrict__ Ag,
                                                 const ushort* __restrict__ Btg,
                                                 const float* __restrict__ biasg,
                                                 ushort* __restrict__ Cout,
                                                 int Mrows, int Ncols, int Kdim) {
  __shared__ ushort sh[65536];   // 128 KiB
  // bijective XCD swizzle (grids are %8==0)
  const int gx = gridDim.x, gy = gridDim.y;
  const int nwg = gx * gy * gridDim.z;
  const int lin = blockIdx.x + gx * (blockIdx.y + gy * blockIdx.z);
  const int cpx = nwg >> 3;
  const int swz = (lin & 7) * cpx + (lin >> 3);
  const int gxy = gx * gy;
  const int ez = swz / gxy;
  const int rem = swz - ez * gxy;
  const int by = rem / gx;
  const int bx = rem - by * gx;

  const ushort* A  = Ag  + (size_t)ez * Mrows * Kdim;
  const ushort* Bt = Btg + (size_t)ez * Ncols * Kdim;
  const float* bias = biasg + (size_t)ez * Ncols;
  ushort* Cptr = Cout + (size_t)ez * Mrows * Ncols;
  const int m0 = by * 256, n0 = bx * 256;
  const int t = threadIdx.x, lane = t & 63, w = t >> 6;
  const int l15 = lane & 15, l4 = lane >> 4;
  const int wr = w >> 2, wc = w & 3;      // 2x4 wave grid over quadrant frags

  // ---- staging addressing ----
  const int srow = lane >> 3;             // 0..7 row within 8-row slab
  const int cs = (lane & 7) ^ srow;       // pre-swizzled source chunk
  const ushort* Abase = A  + (size_t)(m0 + w * 8 + srow) * Kdim + cs * 8;
  const ushort* Bbase = Bt + (size_t)(n0 + w * 8 + srow) * Kdim + cs * 8;
  const int ldsw = w * 512;               // wave-uniform LDS offset (ushorts)

  // stage one half (128 rows x 64 K) of A or B: 2 gloads/thread
#define STAGE8(isA, d, half, ktile)                                          \
  do {                                                                       \
    const ushort* gb = ((isA) ? Abase : Bbase) +                             \
                       (size_t)((half) * 128) * Kdim + (ktile) * 64;         \
    ushort* lb = sh + ((isA) ? 0 : 32768) + ((d) * 2 + (half)) * 8192 + ldsw;\
    GLOAD_LDS16(gb, lb);                                                     \
    GLOAD_LDS16(gb + (size_t)64 * Kdim, lb + 4096);                         \
  } while (0)

  // ---- fragment-read addressing ----
  const int chk0 = ((0 + l4) ^ (l15 & 7)) * 8;   // kk=0 chunk (ushorts)
  const int chk1 = ((4 + l4) ^ (l15 & 7)) * 8;   // kk=1 chunk
  const int aoff = (wr * 64 + l15) * 64;
  const int boff = (wc * 32 + l15) * 64;

  bf16x8 af[8];    // A-frags of current ai: [fr]=kk0, [4+fr]=kk1
  bf16x8 b0[4];    // B0 frags: [fc]=kk0, [2+fc]=kk1 (held q0->q3)
  bf16x8 b1[4];    // B1 frags

#define READ_A(d, ai)                                                        \
  { const ushort* Ar = sh + ((d) * 2 + (ai)) * 8192 + aoff;                  \
    _Pragma("unroll") for (int fr = 0; fr < 4; ++fr) {                       \
      af[fr]     = *(const bf16x8*)(Ar + fr * 1024 + chk0);                  \
      af[4 + fr] = *(const bf16x8*)(Ar + fr * 1024 + chk1);                  \
    } }

#define READ_B(d, bj, dst)                                                   \
  { const ushort* Br = sh + 32768 + ((d) * 2 + (bj)) * 8192 + boff;          \
    _Pragma("unroll") for (int fc = 0; fc < 2; ++fc) {                       \
      dst[fc]     = *(const bf16x8*)(Br + fc * 1024 + chk0);                 \
      dst[2 + fc] = *(const bf16x8*)(Br + fc * 1024 + chk1);                 \
    } }

#define MFMA_Q(ai, bj, BR)                                                   \
  __builtin_amdgcn_s_setprio(1);                                             \
  _Pragma("unroll") for (int fr = 0; fr < 4; ++fr)                           \
    _Pragma("unroll") for (int fc = 0; fc < 2; ++fc) {                       \
      acc[(ai) * 4 + fr][(bj) * 2 + fc] =                                    \
          __builtin_amdgcn_mfma_f32_16x16x32_bf16(                           \
              af[fr], BR[fc], acc[(ai) * 4 + fr][(bj) * 2 + fc], 0, 0, 0);   \
      acc[(ai) * 4 + fr][(bj) * 2 + fc] =                                    \
          __builtin_amdgcn_mfma_f32_16x16x32_bf16(                           \
              af[4 + fr], BR[2 + fc], acc[(ai) * 4 + fr][(bj) * 2 + fc],     \
              0, 0, 0);                                                      \
    }                                                                        \
  __builtin_amdgcn_s_setprio(0);

#define SB  __builtin_amdgcn_sched_barrier(0)
#define BAR __builtin_amdgcn_s_barrier()
#define VM4 asm volatile("s_waitcnt vmcnt(4)" ::: "memory")
#define VM0 asm volatile("s_waitcnt vmcnt(0)" ::: "memory")

  f32x4 acc[8][4];
#pragma unroll
  for (int i = 0; i < 8; ++i)
#pragma unroll
    for (int j = 0; j < 4; ++j) acc[i][j] = (f32x4){0.f, 0.f, 0.f, 0.f};

  const int NT = Kdim >> 6;
  const int NI = NT >> 1;
  // prologue: tile0 all 4 halves + tile1 A0,B1 (matches steady-state invariant)
  STAGE8(1, 0, 0, 0);
  STAGE8(0, 0, 1, 0);
  STAGE8(1, 0, 1, 0);
  STAGE8(0, 0, 0, 0);
  STAGE8(1, 1, 0, 1);
  STAGE8(0, 1, 1, 1);
  VM4;           // 12 outstanding -> drains tile0's 8; tile1 A0,B1 in flight
  SB; BAR;

  for (int t2 = 0; t2 < NI; ++t2) {
    const int tb = 2 * t2;
    const bool g2 = (t2 + 1) < NI;     // tiles tb+2, tb+3 exist
    const bool last = (t2 == NI - 1);
    // ---- tile tb (buf0) ----
    // P0: q0=(A0,B0)
    SB; READ_A(0, 0) READ_B(0, 0, b0) STAGE8(1, 1, 1, tb + 1); SB; BAR;
    MFMA_Q(0, 0, b0) SB; BAR;
    // P1: q1=(A0,B1)  [af held]
    SB; READ_B(0, 1, b1) STAGE8(0, 1, 0, tb + 1); SB; BAR;
    MFMA_Q(0, 1, b1) SB; BAR;
    // P2: q2=(A1,B1)  [b1 held]
    SB; READ_A(0, 1) if (g2) STAGE8(1, 0, 0, tb + 2); SB; BAR;
    MFMA_Q(1, 1, b1) SB; BAR;
    // P3: q3=(A1,B0)  [af, b0 held; no reads]
    SB; if (g2) STAGE8(0, 0, 1, tb + 2); SB; BAR;
    MFMA_Q(1, 0, b0) SB;
    if (last) { VM0; } else { VM4; }   // tile tb+1 fully staged after this
    BAR;
    // ---- tile tb+1 (buf1) ----
    // P4: q0
    SB; READ_A(1, 0) READ_B(1, 0, b0) if (g2) STAGE8(1, 0, 1, tb + 2); SB; BAR;
    MFMA_Q(0, 0, b0) SB; BAR;
    // P5: q1
    SB; READ_B(1, 1, b1) if (g2) STAGE8(0, 0, 0, tb + 2); SB; BAR;
    MFMA_Q(0, 1, b1) SB; BAR;
    // P6: q2
    SB; READ_A(1, 1) if (g2) STAGE8(1, 1, 0, tb + 3); SB; BAR;
    MFMA_Q(1, 1, b1) SB; BAR;
    // P7: q3
    SB; if (g2) STAGE8(0, 1, 1, tb + 3); SB; BAR;
    MFMA_Q(1, 0, b0) SB; VM4; BAR;     // tile tb+2 fully staged after this
  }

  // epilogue: D[row=(l>>4)*4+r][col=l&15] per 16x16 frag
#pragma unroll
  for (int ai = 0; ai < 2; ++ai)
#pragma unroll
    for (int fr = 0; fr < 4; ++fr) {
      const int rowb = m0 + ai * 128 + wr * 64 + fr * 16 + l4 * 4;
#pragma unroll
      for (int bj = 0; bj < 2; ++bj)
#pragma unroll
        for (int fc = 0; fc < 2; ++fc) {
          const int col = n0 + bj * 128 + wc * 32 + fc * 16 + l15;
          const float bv = bias[col];
          f32x4 v = acc[ai * 4 + fr][bj * 2 + fc];
#pragma unroll
          for (int r = 0; r < 4; ++r) {
            float f = v[r] + bv;
            if (RELU) f = fmaxf(f, 0.f);
            Cptr[(size_t)(rowb + r) * Ncols + col] = f2bf(f);
          }
        }
    }
#undef STAGE8
#undef READ_A
#undef READ_B
#undef MFMA_Q
#undef SB
#undef BAR
#undef VM4
#undef VM0
}

// ---------------- combine: out[n] = sum_k gate * y[e_k, p_k] -----------------
__global__ __launch_bounds__(256) void combine_kernel(const ushort* __restrict__ y,
                                                      const int* __restrict__ topi,
                                                      const int* __restrict__ pos,
                                                      const float* __restrict__ gatev,
                                                      float* __restrict__ out) {
  const int lane = threadIdx.x & 63;
  const int n = blockIdx.x * 4 + (threadIdx.x >> 6);
  int i0 = topi[n * 2], i1 = topi[n * 2 + 1];
  int p0 = pos[n * 2], p1 = pos[n * 2 + 1];
  float g0 = (p0 < CAP) ? gatev[n * 2] : 0.f;
  float g1 = (p1 < CAP) ? gatev[n * 2 + 1] : 0.f;
  const ushort* y0 = y + (size_t)(i0 * CAP + (p0 < CAP ? p0 : 0)) * MDIM;
  const ushort* y1 = y + (size_t)(i1 * CAP + (p1 < CAP ? p1 : 0)) * MDIM;
  float* o = out + (size_t)n * MDIM;
#pragma unroll
  for (int c = 0; c < 4; ++c) {
    int idx = c * 256 + lane * 4;
    ushort4 a = *(const ushort4*)(y0 + idx);
    ushort4 b = *(const ushort4*)(y1 + idx);
    float4 ov;
    ov.x = g0 * bf2f(a.x) + g1 * bf2f(b.x);
    ov.y = g0 * bf2f(a.y) + g1 * bf2f(b.y);
    ov.z = g0 * bf2f(a.z) + g1 * bf2f(b.z);
    ov.w = g0 * bf2f(a.w) + g1 * bf2f(b.w);
    *(float4*)(o + idx) = ov;
  }
}

extern "C" void kernel_launch(void* const* d_in, const int* in_sizes, int n_in,
                              void* d_out, int out_size, void* d_ws, size_t ws_size,
                              hipStream_t stream) {
  const float* x  = (const float*)d_in[0];
  const float* wg = (const float*)d_in[1];
  const float* w1 = (const float*)d_in[2];
  const float* b1 = (const float*)d_in[3];
  const float* w2 = (const float*)d_in[4];
  const float* b2 = (const float*)d_in[5];
  float* out = (float*)d_out;
  char* ws = (char*)d_ws;

  // workspace layout (224.3 MB total)
  int*    topi  = (int*)(ws);
  int*    pos   = (int*)(ws + 65536);
  float*  gatev = (float*)(ws + 131072);
  ushort* dispb = (ushort*)(ws + 262144);                          // 32MB, reused as y
  ushort* wT    = (ushort*)(ws + 262144 + 33554432);               // 64MB (w1t then w2t)
  ushort* hbuf  = (ushort*)(ws + 262144 + 33554432 + 67108864);    // 128MB

  gate_kernel<<<NTOK / 4, 256, 0, stream>>>(x, wg, topi, gatev);
  scan_kernel<<<1, 256, 0, stream>>>(topi, pos);
  zero_kernel<<<2048, 256, 0, stream>>>((uint4*)dispb);
  scatter_kernel<<<NTOK / 4, 256, 0, stream>>>(x, topi, pos, dispb);

  // FFN layer 1: h = relu(disp @ w1 + b1)   [E,2048,1024]x[E,1024,4096]
  transpose_cvt<<<dim3(HDIM / 64, MDIM / 64, NEXP), 256, 0, stream>>>(w1, wT, MDIM, HDIM);
  gemm8p<true><<<dim3(HDIM / 256, CAP / 256, NEXP), 512, 0, stream>>>(
      dispb, wT, b1, hbuf, CAP, HDIM, MDIM);

  // FFN layer 2: y = h @ w2 + b2            [E,2048,4096]x[E,4096,1024]
  transpose_cvt<<<dim3(MDIM / 64, HDIM / 64, NEXP), 256, 0, stream>>>(w2, wT, HDIM, MDIM);
  ushort* ybuf = dispb;  // dispb is dead after GEMM1
  gemm8p<false><<<dim3(MDIM / 256, CAP / 256, NEXP), 512, 0, stream>>>(
      hbuf, wT, b2, ybuf, CAP, MDIM, HDIM);

  combine_kernel<<<NTOK / 4, 256, 0, stream>>>(ybuf, topi, pos, gatev, out);
}

// Round 5
// 414.181 us; speedup vs baseline: 1.3618x; 1.0211x over previous
//
#include <hip/hip_runtime.h>
#include <hip/hip_bf16.h>
#include <stdint.h>

#define NTOK 8192   // B*S
#define MDIM 1024
#define HDIM 4096
#define NEXP 8
#define CAP  2048   // int(1.0 * 2 * 8192 // 8)

typedef __attribute__((ext_vector_type(8))) short bf16x8;
typedef __attribute__((ext_vector_type(4))) float f32x4;

__device__ __forceinline__ ushort f2bf(float f) {
  uint32_t u = __builtin_bit_cast(uint32_t, f);
  u += 0x7FFFu + ((u >> 16) & 1u);          // round-to-nearest-even
  return (ushort)(u >> 16);
}
__device__ __forceinline__ float bf2f(ushort h) {
  uint32_t u = ((uint32_t)h) << 16;
  return __builtin_bit_cast(float, u);
}

// async global->LDS, 16B per lane; LDS dest = wave-uniform base + lane*16
#define GLOAD_LDS16(g, l)                                                    \
  __builtin_amdgcn_global_load_lds(                                          \
      (const __attribute__((address_space(1))) void*)(g),                    \
      (__attribute__((address_space(3))) void*)(l), 16, 0, 0)

// ---------------- gate: logits = x@wg (f64 accum), softmax-top2, normalize ----
__global__ __launch_bounds__(256) void gate_kernel(const float* __restrict__ x,
                                                   const float* __restrict__ wg,
                                                   int* __restrict__ topi,
                                                   float* __restrict__ gatev) {
  const int lane = threadIdx.x & 63;
  const int n = blockIdx.x * 4 + (threadIdx.x >> 6);   // one wave per token
  const float* xr = x + (size_t)n * MDIM;
  double acc[NEXP];
#pragma unroll
  for (int e = 0; e < NEXP; ++e) acc[e] = 0.0;
#pragma unroll
  for (int c = 0; c < 4; ++c) {
    float4 xv = *(const float4*)(xr + c * 256 + lane * 4);
    float xs[4] = {xv.x, xv.y, xv.z, xv.w};
#pragma unroll
    for (int j = 0; j < 4; ++j) {
      int m = c * 256 + lane * 4 + j;
      float4 w0 = *(const float4*)(wg + m * 8);
      float4 w1 = *(const float4*)(wg + m * 8 + 4);
      double xd = (double)xs[j];
      acc[0] += xd * (double)w0.x; acc[1] += xd * (double)w0.y;
      acc[2] += xd * (double)w0.z; acc[3] += xd * (double)w0.w;
      acc[4] += xd * (double)w1.x; acc[5] += xd * (double)w1.y;
      acc[6] += xd * (double)w1.z; acc[7] += xd * (double)w1.w;
    }
  }
#pragma unroll
  for (int off = 32; off >= 1; off >>= 1) {
#pragma unroll
    for (int e = 0; e < NEXP; ++e) acc[e] += __shfl_xor(acc[e], off, 64);
  }
  if (lane == 0) {
    int i0 = 0;
#pragma unroll
    for (int e = 1; e < NEXP; ++e) if (acc[e] > acc[i0]) i0 = e;
    int i1 = (i0 == 0) ? 1 : 0;
#pragma unroll
    for (int e = 0; e < NEXP; ++e) if (e != i0 && acc[e] > acc[i1]) i1 = e;
    // normalized top-2 of softmax == softmax over the two logits
    double e1 = exp(acc[i1] - acc[i0]);
    double s = 1.0 + e1;
    topi[n * 2 + 0] = i0; topi[n * 2 + 1] = i1;
    gatev[n * 2 + 0] = (float)(1.0 / s);
    gatev[n * 2 + 1] = (float)(e1 / s);
  }
}

// ---------------- slot-major cumulative positions (order: j = k*NTOK + n) ----
__global__ __launch_bounds__(256) void scan_kernel(const int* __restrict__ topi,
                                                   int* __restrict__ pos) {
  __shared__ int cnt[256][NEXP];
  const int t = threadIdx.x;
#pragma unroll
  for (int e = 0; e < NEXP; ++e) cnt[t][e] = 0;
  for (int i = 0; i < 64; ++i) {
    int j = t * 64 + i;
    int e = topi[(j & (NTOK - 1)) * 2 + (j >> 13)];
    cnt[t][e]++;
  }
  __syncthreads();
  if (t < NEXP) {          // exclusive scan over the 256 thread-chunks
    int run = 0;
    for (int i = 0; i < 256; ++i) { int v = cnt[i][t]; cnt[i][t] = run; run += v; }
  }
  __syncthreads();
  for (int i = 0; i < 64; ++i) {
    int j = t * 64 + i;
    int idx = (j & (NTOK - 1)) * 2 + (j >> 13);
    int e = topi[idx];
    pos[idx] = cnt[t][e]++;
  }
}

// ---------------- zero the dispatch buffer -----------------------------------
__global__ __launch_bounds__(256) void zero_kernel(uint4* __restrict__ p) {
  int t = blockIdx.x * 256 + threadIdx.x;
#pragma unroll
  for (int i = 0; i < 4; ++i) {
    uint4 z; z.x = 0; z.y = 0; z.z = 0; z.w = 0;
    p[t + i * 524288] = z;   // 2048 blocks * 256 thr * 4 * 16B = 32MB
  }
}

// ---------------- scatter x rows (bf16) into [E,CAP,M] -----------------------
__global__ __launch_bounds__(256) void scatter_kernel(const float* __restrict__ x,
                                                      const int* __restrict__ topi,
                                                      const int* __restrict__ pos,
                                                      ushort* __restrict__ disp) {
  const int lane = threadIdx.x & 63;
  const int n = blockIdx.x * 4 + (threadIdx.x >> 6);
  const float* src = x + (size_t)n * MDIM;
  ushort b[16];
#pragma unroll
  for (int c = 0; c < 4; ++c) {
    float4 v = *(const float4*)(src + c * 256 + lane * 4);
    b[c * 4 + 0] = f2bf(v.x); b[c * 4 + 1] = f2bf(v.y);
    b[c * 4 + 2] = f2bf(v.z); b[c * 4 + 3] = f2bf(v.w);
  }
#pragma unroll
  for (int k = 0; k < 2; ++k) {
    int p = pos[n * 2 + k];
    if (p < CAP) {
      int e = topi[n * 2 + k];
      ushort* dst = disp + ((size_t)(e * CAP + p)) * MDIM;
#pragma unroll
      for (int c = 0; c < 4; ++c) {
        ushort4 o; o.x = b[c*4+0]; o.y = b[c*4+1]; o.z = b[c*4+2]; o.w = b[c*4+3];
        *(ushort4*)(dst + c * 256 + lane * 4) = o;
      }
    }
  }
}

// ---------------- transpose + f32->bf16: in[R][C] -> out[C][R], per expert ---
__global__ __launch_bounds__(256) void transpose_cvt(const float* __restrict__ in,
                                                     ushort* __restrict__ out,
                                                     int R, int C) {
  __shared__ float tile[64][65];
  const int e = blockIdx.z;
  in  += (size_t)e * R * C;
  out += (size_t)e * R * C;
  const int r0 = blockIdx.y * 64, c0 = blockIdx.x * 64;
  const int t = threadIdx.x;
  const int r = t >> 2, cq = t & 3;
#pragma unroll
  for (int i = 0; i < 4; ++i) {
    float4 v = *(const float4*)(in + (size_t)(r0 + r) * C + c0 + cq * 16 + i * 4);
    tile[r][cq * 16 + i * 4 + 0] = v.x; tile[r][cq * 16 + i * 4 + 1] = v.y;
    tile[r][cq * 16 + i * 4 + 2] = v.z; tile[r][cq * 16 + i * 4 + 3] = v.w;
  }
  __syncthreads();
  const int oc = t >> 2, orr0 = (t & 3) * 16;
  ushort o16[16];
#pragma unroll
  for (int i = 0; i < 16; ++i) o16[i] = f2bf(tile[orr0 + i][oc]);
  ushort* dst = out + (size_t)(c0 + oc) * R + r0 + orr0;
  *(uint4*)dst = *(uint4*)&o16[0];
  *(uint4*)(dst + 8) = *(uint4*)&o16[8];
}

// ============================================================================
// 256x256x64 bf16 GEMM, merged-window schedule (round 5):
// Quadrant walk q0=(A0,B0) q1=(A0,B1) q2=(A1,B1) q3=(A1,B0); A-frags held
// across quadrant pairs, B0 held q0->q3 (24 ds_read_b128/tile/wave).
// TWO barrier windows per K-tile (W0=q0+q1, W1=q2+q3): reads, stage issue
// and MFMA share a window; per-wave correctness via compiler lgkmcnt, the
// CU-level LDS pipe overlaps other waves' MFMA (round-4 structure serialized
// them: 2480cy MFMA + 2300cy LDS alternating = measured 5520cy/tile).
// Counted vmcnt(4) at W1/W3 ends (VM0 at last-iter W1). Ledger re-verified
// at the new barrier positions: all same-window stage targets disjoint from
// that window's reads; stage-vs-read pairs >=1 barrier apart with reads
// consumed by MFMA before that barrier.
// ============================================================================
template <bool RELU>
__global__ __launch_bounds__(512, 1) void gemm8p(const ushort* __restrict__ Ag,
                                                 const ushort* __restrict__ Btg,
                                                 const float* __restrict__ biasg,
                                                 ushort* __restrict__ Cout,
                                                 int Mrows, int Ncols, int Kdim) {
  __shared__ ushort sh[65536];   // 128 KiB
  // bijective XCD swizzle (grids are %8==0)
  const int gx = gridDim.x, gy = gridDim.y;
  const int nwg = gx * gy * gridDim.z;
  const int lin = blockIdx.x + gx * (blockIdx.y + gy * blockIdx.z);
  const int cpx = nwg >> 3;
  const int swz = (lin & 7) * cpx + (lin >> 3);
  const int gxy = gx * gy;
  const int ez = swz / gxy;
  const int rem = swz - ez * gxy;
  const int by = rem / gx;
  const int bx = rem - by * gx;

  const ushort* A  = Ag  + (size_t)ez * Mrows * Kdim;
  const ushort* Bt = Btg + (size_t)ez * Ncols * Kdim;
  const float* bias = biasg + (size_t)ez * Ncols;
  ushort* Cptr = Cout + (size_t)ez * Mrows * Ncols;
  const int m0 = by * 256, n0 = bx * 256;
  const int t = threadIdx.x, lane = t & 63, w = t >> 6;
  const int l15 = lane & 15, l4 = lane >> 4;
  const int wr = w >> 2, wc = w & 3;      // 2x4 wave grid over quadrant frags

  // ---- staging addressing ----
  const int srow = lane >> 3;             // 0..7 row within 8-row slab
  const int cs = (lane & 7) ^ srow;       // pre-swizzled source chunk
  const ushort* Abase = A  + (size_t)(m0 + w * 8 + srow) * Kdim + cs * 8;
  const ushort* Bbase = Bt + (size_t)(n0 + w * 8 + srow) * Kdim + cs * 8;
  const int ldsw = w * 512;               // wave-uniform LDS offset (ushorts)

  // stage one half (128 rows x 64 K) of A or B: 2 gloads/thread
#define STAGE8(isA, d, half, ktile)                                          \
  do {                                                                       \
    const ushort* gb = ((isA) ? Abase : Bbase) +                             \
                       (size_t)((half) * 128) * Kdim + (ktile) * 64;         \
    ushort* lb = sh + ((isA) ? 0 : 32768) + ((d) * 2 + (half)) * 8192 + ldsw;\
    GLOAD_LDS16(gb, lb);                                                     \
    GLOAD_LDS16(gb + (size_t)64 * Kdim, lb + 4096);                         \
  } while (0)

  // ---- fragment-read addressing ----
  const int chk0 = ((0 + l4) ^ (l15 & 7)) * 8;   // kk=0 chunk (ushorts)
  const int chk1 = ((4 + l4) ^ (l15 & 7)) * 8;   // kk=1 chunk
  const int aoff = (wr * 64 + l15) * 64;
  const int boff = (wc * 32 + l15) * 64;

  bf16x8 af[8];    // A-frags of current ai: [fr]=kk0, [4+fr]=kk1
  bf16x8 b0[4];    // B0 frags: [fc]=kk0, [2+fc]=kk1 (held q0->q3)
  bf16x8 b1[4];    // B1 frags

#define READ_A(d, ai)                                                        \
  { const ushort* Ar = sh + ((d) * 2 + (ai)) * 8192 + aoff;                  \
    _Pragma("unroll") for (int fr = 0; fr < 4; ++fr) {                       \
      af[fr]     = *(const bf16x8*)(Ar + fr * 1024 + chk0);                  \
      af[4 + fr] = *(const bf16x8*)(Ar + fr * 1024 + chk1);                  \
    } }

#define READ_B(d, bj, dst)                                                   \
  { const ushort* Br = sh + 32768 + ((d) * 2 + (bj)) * 8192 + boff;          \
    _Pragma("unroll") for (int fc = 0; fc < 2; ++fc) {                       \
      dst[fc]     = *(const bf16x8*)(Br + fc * 1024 + chk0);                 \
      dst[2 + fc] = *(const bf16x8*)(Br + fc * 1024 + chk1);                 \
    } }

#define MFMA_Q(ai, bj, BR)                                                   \
  __builtin_amdgcn_s_setprio(1);                                             \
  _Pragma("unroll") for (int fr = 0; fr < 4; ++fr)                           \
    _Pragma("unroll") for (int fc = 0; fc < 2; ++fc) {                       \
      acc[(ai) * 4 + fr][(bj) * 2 + fc] =                                    \
          __builtin_amdgcn_mfma_f32_16x16x32_bf16(                           \
              af[fr], BR[fc], acc[(ai) * 4 + fr][(bj) * 2 + fc], 0, 0, 0);   \
      acc[(ai) * 4 + fr][(bj) * 2 + fc] =                                    \
          __builtin_amdgcn_mfma_f32_16x16x32_bf16(                           \
              af[4 + fr], BR[2 + fc], acc[(ai) * 4 + fr][(bj) * 2 + fc],     \
              0, 0, 0);                                                      \
    }                                                                        \
  __builtin_amdgcn_s_setprio(0);

#define SB  __builtin_amdgcn_sched_barrier(0)
#define BAR __builtin_amdgcn_s_barrier()
#define VM4 asm volatile("s_waitcnt vmcnt(4)" ::: "memory")
#define VM0 asm volatile("s_waitcnt vmcnt(0)" ::: "memory")

  f32x4 acc[8][4];
#pragma unroll
  for (int i = 0; i < 8; ++i)
#pragma unroll
    for (int j = 0; j < 4; ++j) acc[i][j] = (f32x4){0.f, 0.f, 0.f, 0.f};

  const int NT = Kdim >> 6;
  const int NI = NT >> 1;
  // prologue: tile0 all 4 halves + tile1 A0,B1 (steady-state invariant)
  STAGE8(1, 0, 0, 0);
  STAGE8(0, 0, 1, 0);
  STAGE8(1, 0, 1, 0);
  STAGE8(0, 0, 0, 0);
  STAGE8(1, 1, 0, 1);
  STAGE8(0, 1, 1, 1);
  VM4;           // 12 outstanding -> drains tile0's 8; tile1 A0,B1 in flight
  SB; BAR;

  for (int t2 = 0; t2 < NI; ++t2) {
    const int tb = 2 * t2;
    const bool g2 = (t2 + 1) < NI;     // tiles tb+2, tb+3 exist
    const bool last = (t2 == NI - 1);
    // ---- W0: tile tb (buf0), q0+q1 ----
    READ_A(0, 0) READ_B(0, 0, b0)
    STAGE8(1, 1, 1, tb + 1);           // A1 of t+1 -> d1
    STAGE8(0, 1, 0, tb + 1);           // B0 of t+1 -> d1
    READ_B(0, 1, b1)
    MFMA_Q(0, 0, b0)
    MFMA_Q(0, 1, b1)
    SB; BAR;
    // ---- W1: tile tb, q2+q3 ----
    READ_A(0, 1)
    if (g2) { STAGE8(1, 0, 0, tb + 2); STAGE8(0, 0, 1, tb + 2); } // A0,B1 t+2 -> d0
    MFMA_Q(1, 1, b1)
    MFMA_Q(1, 0, b0)
    SB;
    if (last) { VM0; } else { VM4; }   // t+1 (d1) fully staged after this
    BAR;
    // ---- W2: tile tb+1 (buf1), q0+q1 ----
    READ_A(1, 0) READ_B(1, 0, b0)
    if (g2) { STAGE8(1, 0, 1, tb + 2); STAGE8(0, 0, 0, tb + 2); } // A1,B0 t+2 -> d0
    READ_B(1, 1, b1)
    MFMA_Q(0, 0, b0)
    MFMA_Q(0, 1, b1)
    SB; BAR;
    // ---- W3: tile tb+1, q2+q3 ----
    READ_A(1, 1)
    if (g2) { STAGE8(1, 1, 0, tb + 3); STAGE8(0, 1, 1, tb + 3); } // A0,B1 t+3 -> d1
    MFMA_Q(1, 1, b1)
    MFMA_Q(1, 0, b0)
    SB; VM4; BAR;                      // t+2 (d0) fully staged after this
  }

  // epilogue: D[row=(l>>4)*4+r][col=l&15] per 16x16 frag
#pragma unroll
  for (int ai = 0; ai < 2; ++ai)
#pragma unroll
    for (int fr = 0; fr < 4; ++fr) {
      const int rowb = m0 + ai * 128 + wr * 64 + fr * 16 + l4 * 4;
#pragma unroll
      for (int bj = 0; bj < 2; ++bj)
#pragma unroll
        for (int fc = 0; fc < 2; ++fc) {
          const int col = n0 + bj * 128 + wc * 32 + fc * 16 + l15;
          const float bv = bias[col];
          f32x4 v = acc[ai * 4 + fr][bj * 2 + fc];
#pragma unroll
          for (int r = 0; r < 4; ++r) {
            float f = v[r] + bv;
            if (RELU) f = fmaxf(f, 0.f);
            Cptr[(size_t)(rowb + r) * Ncols + col] = f2bf(f);
          }
        }
    }
#undef STAGE8
#undef READ_A
#undef READ_B
#undef MFMA_Q
#undef SB
#undef BAR
#undef VM4
#undef VM0
}

// ---------------- combine: out[n] = sum_k gate * y[e_k, p_k] -----------------
__global__ __launch_bounds__(256) void combine_kernel(const ushort* __restrict__ y,
                                                      const int* __restrict__ topi,
                                                      const int* __restrict__ pos,
                                                      const float* __restrict__ gatev,
                                                      float* __restrict__ out) {
  const int lane = threadIdx.x & 63;
  const int n = blockIdx.x * 4 + (threadIdx.x >> 6);
  int i0 = topi[n * 2], i1 = topi[n * 2 + 1];
  int p0 = pos[n * 2], p1 = pos[n * 2 + 1];
  float g0 = (p0 < CAP) ? gatev[n * 2] : 0.f;
  float g1 = (p1 < CAP) ? gatev[n * 2 + 1] : 0.f;
  const ushort* y0 = y + (size_t)(i0 * CAP + (p0 < CAP ? p0 : 0)) * MDIM;
  const ushort* y1 = y + (size_t)(i1 * CAP + (p1 < CAP ? p1 : 0)) * MDIM;
  float* o = out + (size_t)n * MDIM;
#pragma unroll
  for (int c = 0; c < 4; ++c) {
    int idx = c * 256 + lane * 4;
    ushort4 a = *(const ushort4*)(y0 + idx);
    ushort4 b = *(const ushort4*)(y1 + idx);
    float4 ov;
    ov.x = g0 * bf2f(a.x) + g1 * bf2f(b.x);
    ov.y = g0 * bf2f(a.y) + g1 * bf2f(b.y);
    ov.z = g0 * bf2f(a.z) + g1 * bf2f(b.z);
    ov.w = g0 * bf2f(a.w) + g1 * bf2f(b.w);
    *(float4*)(o + idx) = ov;
  }
}

extern "C" void kernel_launch(void* const* d_in, const int* in_sizes, int n_in,
                              void* d_out, int out_size, void* d_ws, size_t ws_size,
                              hipStream_t stream) {
  const float* x  = (const float*)d_in[0];
  const float* wg = (const float*)d_in[1];
  const float* w1 = (const float*)d_in[2];
  const float* b1 = (const float*)d_in[3];
  const float* w2 = (const float*)d_in[4];
  const float* b2 = (const float*)d_in[5];
  float* out = (float*)d_out;
  char* ws = (char*)d_ws;

  // workspace layout (224.3 MB total)
  int*    topi  = (int*)(ws);
  int*    pos   = (int*)(ws + 65536);
  float*  gatev = (float*)(ws + 131072);
  ushort* dispb = (ushort*)(ws + 262144);                          // 32MB, reused as y
  ushort* wT    = (ushort*)(ws + 262144 + 33554432);               // 64MB (w1t then w2t)
  ushort* hbuf  = (ushort*)(ws + 262144 + 33554432 + 67108864);    // 128MB

  gate_kernel<<<NTOK / 4, 256, 0, stream>>>(x, wg, topi, gatev);
  scan_kernel<<<1, 256, 0, stream>>>(topi, pos);
  zero_kernel<<<2048, 256, 0, stream>>>((uint4*)dispb);
  scatter_kernel<<<NTOK / 4, 256, 0, stream>>>(x, topi, pos, dispb);

  // FFN layer 1: h = relu(disp @ w1 + b1)   [E,2048,1024]x[E,1024,4096]
  transpose_cvt<<<dim3(HDIM / 64, MDIM / 64, NEXP), 256, 0, stream>>>(w1, wT, MDIM, HDIM);
  gemm8p<true><<<dim3(HDIM / 256, CAP / 256, NEXP), 512, 0, stream>>>(
      dispb, wT, b1, hbuf, CAP, HDIM, MDIM);

  // FFN layer 2: y = h @ w2 + b2            [E,2048,4096]x[E,4096,1024]
  transpose_cvt<<<dim3(MDIM / 64, HDIM / 64, NEXP), 256, 0, stream>>>(w2, wT, HDIM, MDIM);
  ushort* ybuf = dispb;  // dispb is dead after GEMM1
  gemm8p<false><<<dim3(MDIM / 256, CAP / 256, NEXP), 512, 0, stream>>>(
      hbuf, wT, b2, ybuf, CAP, MDIM, HDIM);

  combine_kernel<<<NTOK / 4, 256, 0, stream>>>(ybuf, topi, pos, gatev, out);
}